// Round 26
// baseline (92.567 us; speedup 1.0000x reference)
//
#include <hip/hip_runtime.h>
#include <hip/hip_bf16.h>
#include <math.h>

#define BS 4096
#define DIM 2048
#define EPSV 1e-6f

typedef unsigned char u8;
typedef unsigned long long u64;
typedef long i64;
typedef float f32x4 __attribute__((ext_vector_type(4)));

// f32 -> e4m3fn (OCP), RNE, FTZ below 2^-6, clamp to 448 (R17/R19/R21-verified: absmax 0.0).
__device__ inline u8 f2e4m3(float f) {
  unsigned u = __float_as_uint(f);
  unsigned s = (u >> 24) & 0x80u;
  unsigned ae = u & 0x7FFFFFFFu;
  if (ae < 0x3C800000u) return (u8)s;
  if (ae > 0x43E00000u) ae = 0x43E00000u;
  unsigned r = ae + 0x7FFFFu + ((ae >> 20) & 1u);
  unsigned e = (r >> 23) & 0xFFu;
  return (u8)(s | ((e - 120u) << 3) | ((r >> 20) & 7u));
}

__device__ inline void gload16(const u8* g, u8* l_) {
  __builtin_amdgcn_global_load_lds((const __attribute__((address_space(1))) unsigned int*)g,
                                   (__attribute__((address_space(3))) unsigned int*)l_,
                                   16, 0, 0);
}

// ---------------- prep: f32 -> fp8 e4m3 PRE-SWIZZLED + per-row sum / sumsq (R19-verified) -------
__global__ __launch_bounds__(256) void prep_kernel(
    const float* __restrict__ h1, const float* __restrict__ h2,
    u8* __restrict__ A, u8* __restrict__ B,
    float* __restrict__ sq1, float* __restrict__ s1,
    float* __restrict__ sq2, float* __restrict__ s2) {
  int b = blockIdx.x;
  const float* src; u8* dst; float* sqo; float* so; int row;
  if (b < BS) { src = h1; dst = A; sqo = sq1; so = s1; row = b; }
  else        { src = h2; dst = B; sqo = sq2; so = s2; row = b - BS; }
  src += (size_t)row * DIM;
  dst += (size_t)row * DIM;
  int t = threadIdx.x;
  int idx = t * 8;
  float4 v0 = *(const float4*)(src + idx);
  float4 v1 = *(const float4*)(src + idx + 4);
  float sq = v0.x*v0.x + v0.y*v0.y + v0.z*v0.z + v0.w*v0.w
           + v1.x*v1.x + v1.y*v1.y + v1.z*v1.z + v1.w*v1.w;
  float s  = v0.x + v0.y + v0.z + v0.w + v1.x + v1.y + v1.z + v1.w;
  u64 pk = (u64)f2e4m3(v0.x)
         | ((u64)f2e4m3(v0.y) << 8)
         | ((u64)f2e4m3(v0.z) << 16)
         | ((u64)f2e4m3(v0.w) << 24)
         | ((u64)f2e4m3(v1.x) << 32)
         | ((u64)f2e4m3(v1.y) << 40)
         | ((u64)f2e4m3(v1.z) << 48)
         | ((u64)f2e4m3(v1.w) << 56);
  int vswz = (row >> 2) & 3;
  int dstIdx = (t >> 2) * 32 + (((t & 3) ^ vswz) << 3);
  *(u64*)(dst + dstIdx) = pk;
#pragma unroll
  for (int m = 32; m; m >>= 1) { sq += __shfl_xor(sq, m, 64); s += __shfl_xor(s, m, 64); }
  __shared__ float lsq[4], ls[4];
  if ((t & 63) == 0) { lsq[t >> 6] = sq; ls[t >> 6] = s; }
  __syncthreads();
  if (t == 0) {
    sqo[row] = lsq[0] + lsq[1] + lsq[2] + lsq[3];
    so[row]  = ls[0] + ls[1] + ls[2] + ls[3];
  }
}

// ---------------- GEMM (fp8 e4m3): 128x128 tile, BK=128 (4x K32 subtiles), dbuf, 2 blocks/CU ----
// 16 __syncthreads total (vs R25's 32; per-barrier dead time measured ~0.38us).
// 512 thr = 8 waves (4M x 2N), wave tile 32x64, acc[2][4]=32 regs (pressure DOWN vs R25).
// LDS = 2 buf x 4 subtiles x [A 4KB | B 4KB] = 64 KB -> 2 blocks/CU = 16 waves/CU.
// Per-subtile layout/swizzle identical to R19 (row-swizzle (row>>2)&3 == (c>>2)&3 since
// wr*32, mi*16, wc*64 all == 0 mod 16). Epilogue column structure byte-identical to R19.
// Staging: tid<256 stages A rows, tid>=256 stages B rows (1 gload16/thread/subtile).
#define BK128 128
#define NT128 (DIM / BK128)

__global__ __launch_bounds__(512, 4) void gemm_select_kernel(
    const u8* __restrict__ A, const u8* __restrict__ B,
    const float* __restrict__ sq1, const float* __restrict__ s1,
    const float* __restrict__ sq2, const float* __restrict__ s2,
    const int* __restrict__ lab1, const int* __restrict__ lab2,
    float4* __restrict__ part) {
  __shared__ __align__(16) u8 lds[2][4][8192];  // [buf][subtile][A 4096 | B 4096]
  int tid = threadIdx.x;
  int w = tid >> 6, l = tid & 63;
  int wr = w >> 1, wc = w & 1;     // 4M x 2N
  int g = l >> 4, c = l & 15;
  int by = blockIdx.x >> 5, bx = blockIdx.x & 31;
  const int rowB = by * 128, colB = bx * 128;

  // staging (R19 formulas, split A/B across thread halves): 2 lanes per 32B row
  int t2 = tid & 255;
  int srow = t2 >> 1;
  int khalf = (t2 & 1) * 16;
  const u8* gsrc = (tid < 256)
      ? A + (size_t)(rowB + srow) * DIM + khalf
      : B + (size_t)(colB + srow) * DIM + khalf;
  int ldst = (tid < 256 ? 0 : 4096) + t2 * 16;

#define STAGE(T) do { int b_ = (T) & 1; size_t k_ = (size_t)(T) * BK128;  \
    _Pragma("unroll") for (int st_ = 0; st_ < 4; ++st_)                    \
      gload16(gsrc + k_ + st_ * 32, &lds[b_][st_][ldst]); } while (0)

  // fragment reads: slot = g ^ ((c>>2)&3) -> conflict-free b64 (R18/R19-verified)
  const int slot = (g ^ ((c >> 2) & 3)) * 8;

  f32x4 acc[2][4] = {};

  STAGE(0);
  __syncthreads();

  for (int kt = 0; kt < NT128; ++kt) {
    if (kt + 1 < NT128) STAGE(kt + 1);
#pragma unroll
    for (int st = 0; st < 4; ++st) {
      const u8* buf = lds[kt & 1][st];
      i64 af[2], bfr[4];
#pragma unroll
      for (int mi = 0; mi < 2; ++mi)
        af[mi] = *(const i64*)&buf[(wr * 32 + mi * 16 + c) * 32 + slot];
#pragma unroll
      for (int ni = 0; ni < 4; ++ni)
        bfr[ni] = *(const i64*)&buf[4096 + (wc * 64 + ni * 16 + c) * 32 + slot];
#pragma unroll
      for (int mi = 0; mi < 2; ++mi)
#pragma unroll
        for (int ni = 0; ni < 4; ++ni)
          acc[mi][ni] = __builtin_amdgcn_mfma_f32_16x16x32_fp8_fp8(af[mi], bfr[ni], acc[mi][ni], 0, 0, 0);
    }
    __syncthreads();
  }
#undef STAGE

  // --- epilogue: dist + fused hard-pos/neg partial select (columns identical to R19) ---
  float pc_[4]; int l2v[4]; int jcol[4];
#pragma unroll
  for (int ni = 0; ni < 4; ++ni) {
    int j = colB + wc * 64 + ni * 16 + c;
    jcol[ni] = j;
    l2v[ni] = lab2[j];
    pc_[ni] = sq2[j] - 2.0f * EPSV * s2[j];
  }
  const float cst = (float)DIM * EPSV * EPSV;
  int partCol = bx * 2 + wc;

#pragma unroll
  for (int mi = 0; mi < 2; ++mi) {
    float posV[4], negV[4]; int posI[4], negI[4];
    float pr[4]; int l1v[4];
#pragma unroll
    for (int r = 0; r < 4; ++r) {
      int i = rowB + wr * 32 + mi * 16 + g * 4 + r;
      l1v[r] = lab1[i];
      pr[r] = sq1[i] + 2.0f * EPSV * s1[i] + cst;
      posV[r] = -3.0e38f; posI[r] = 0x7fffffff;
      negV[r] =  3.0e38f; negI[r] = 0x7fffffff;
    }
#pragma unroll
    for (int ni = 0; ni < 4; ++ni) {
#pragma unroll
      for (int r = 0; r < 4; ++r) {
        float dot = acc[mi][ni][r];
        float d2 = pr[r] + pc_[ni] - 2.0f * dot;
        float dist = sqrtf(fmaxf(d2, 0.0f));
        bool same = (l1v[r] == l2v[ni]);
        float pv = same ? dist : -3.0e38f;
        float nv = same ?  3.0e38f : dist;
        if (pv > posV[r] || (pv == posV[r] && jcol[ni] < posI[r])) { posV[r] = pv; posI[r] = jcol[ni]; }
        if (nv < negV[r] || (nv == negV[r] && jcol[ni] < negI[r])) { negV[r] = nv; negI[r] = jcol[ni]; }
      }
    }
#pragma unroll
    for (int m = 1; m < 16; m <<= 1) {
#pragma unroll
      for (int r = 0; r < 4; ++r) {
        float ov = __shfl_xor(posV[r], m, 64);
        int   oi = __shfl_xor(posI[r], m, 64);
        if (ov > posV[r] || (ov == posV[r] && oi < posI[r])) { posV[r] = ov; posI[r] = oi; }
        float nv2 = __shfl_xor(negV[r], m, 64);
        int   on  = __shfl_xor(negI[r], m, 64);
        if (nv2 < negV[r] || (nv2 == negV[r] && on < negI[r])) { negV[r] = nv2; negI[r] = on; }
      }
    }
    if (c == 0) {
#pragma unroll
      for (int r = 0; r < 4; ++r) {
        int i = rowB + wr * 32 + mi * 16 + g * 4 + r;
        float4 o;
        o.x = posV[r]; o.y = __int_as_float(posI[r]);
        o.z = negV[r]; o.w = __int_as_float(negI[r]);
        part[(size_t)i * 64 + partCol] = o;
      }
    }
  }
}

// ---------------- combine 64 partials per row -> per-row loss directly (R21-verified) -----------
__global__ __launch_bounds__(256) void reduce_kernel(const float4* __restrict__ part,
                                                     float* __restrict__ perrow,
                                                     float* __restrict__ validf) {
  int row = blockIdx.x * 4 + (threadIdx.x >> 6);
  int lane = threadIdx.x & 63;
  float4 p = part[(size_t)row * 64 + lane];
  float posV = p.x; int posI = __float_as_int(p.y);
  float negV = p.z; int negI = __float_as_int(p.w);
#pragma unroll
  for (int m = 1; m < 64; m <<= 1) {
    float ov = __shfl_xor(posV, m, 64);
    int   oi = __shfl_xor(posI, m, 64);
    if (ov > posV || (ov == posV && oi < posI)) { posV = ov; posI = oi; }
    float nv = __shfl_xor(negV, m, 64);
    int   on = __shfl_xor(negI, m, 64);
    if (nv < negV || (nv == negV && on < negI)) { negV = nv; negI = on; }
  }
  if (lane == 0) {
    bool valid = (posV > -1.0e38f && negV < 1.0e38f);
    perrow[row] = valid ? fmaxf(posV - negV, 0.0f) : 0.0f;
    validf[row] = valid ? 1.0f : 0.0f;
  }
}

// ---------------- deterministic finalize (fixed-order tree) ----------------
__global__ __launch_bounds__(256) void finalize_kernel(const float* __restrict__ perrow,
                                                       const float* __restrict__ validf,
                                                       float* __restrict__ out) {
  int t = threadIdx.x;
  float s = 0.f, cv = 0.f;
  for (int i = t; i < BS; i += 256) { s += perrow[i]; cv += validf[i]; }
  __shared__ float ls[256], lc[256];
  ls[t] = s; lc[t] = cv;
  __syncthreads();
  for (int m = 128; m; m >>= 1) {
    if (t < m) { ls[t] += ls[t + m]; lc[t] += lc[t + m]; }
    __syncthreads();
  }
  if (t == 0) out[0] = (lc[0] > 0.f) ? ls[0] / fmaxf(lc[0], 1.f) : 0.f;
}

extern "C" void kernel_launch(void* const* d_in, const int* in_sizes, int n_in,
                              void* d_out, int out_size, void* d_ws, size_t ws_size,
                              hipStream_t stream) {
  const float* h1 = (const float*)d_in[0];
  const float* h2 = (const float*)d_in[1];
  const int* lab1 = (const int*)d_in[2];
  const int* lab2 = (const int*)d_in[3];

  char* ws = (char*)d_ws;
  u8* A = (u8*)ws;
  u8* B = (u8*)(ws + (size_t)BS * DIM);
  size_t off = (size_t)BS * DIM * 2;
  float* sq1 = (float*)(ws + off); off += BS * 4;
  float* s1  = (float*)(ws + off); off += BS * 4;
  float* sq2 = (float*)(ws + off); off += BS * 4;
  float* s2  = (float*)(ws + off); off += BS * 4;
  float4* part = (float4*)(ws + off); off += (size_t)BS * 64 * 16;
  float* perrow = (float*)(ws + off); off += BS * 4;
  float* validf = (float*)(ws + off); off += BS * 4;

  prep_kernel<<<2 * BS, 256, 0, stream>>>(h1, h2, A, B, sq1, s1, sq2, s2);
  gemm_select_kernel<<<1024, 512, 0, stream>>>(A, B, sq1, s1, sq2, s2, lab1, lab2, part);
  reduce_kernel<<<BS / 4, 256, 0, stream>>>(part, perrow, validf);
  finalize_kernel<<<1, 256, 0, stream>>>(perrow, validf, (float*)d_out);
}

// Round 27
// 92.254 us; speedup vs baseline: 1.0034x; 1.0034x over previous
//
#include <hip/hip_runtime.h>
#include <hip/hip_bf16.h>
#include <math.h>

#define BS 4096
#define DIM 2048
#define EPSV 1e-6f

typedef unsigned char u8;
typedef unsigned long long u64;
typedef long i64;
typedef float f32x4 __attribute__((ext_vector_type(4)));

// f32 -> e4m3fn (OCP), RNE, FTZ below 2^-6, clamp to 448 (R17/R19/R21/R25-verified: absmax 0.0).
__device__ inline u8 f2e4m3(float f) {
  unsigned u = __float_as_uint(f);
  unsigned s = (u >> 24) & 0x80u;
  unsigned ae = u & 0x7FFFFFFFu;
  if (ae < 0x3C800000u) return (u8)s;
  if (ae > 0x43E00000u) ae = 0x43E00000u;
  unsigned r = ae + 0x7FFFFu + ((ae >> 20) & 1u);
  unsigned e = (r >> 23) & 0xFFu;
  return (u8)(s | ((e - 120u) << 3) | ((r >> 20) & 7u));
}

__device__ inline void gload16(const u8* g, u8* l_) {
  __builtin_amdgcn_global_load_lds((const __attribute__((address_space(1))) unsigned int*)g,
                                   (__attribute__((address_space(3))) unsigned int*)l_,
                                   16, 0, 0);
}

// ---------------- prep: f32 -> fp8 e4m3 PRE-SWIZZLED + per-row sum / sumsq (R19-verified) -------
// Within each 32B K-group, store 8B slot s at position s ^ ((row>>2)&3). GEMM stages
// LINEAR (coalesced gload16) and reads conflict-free at slot = g ^ ((c>>2)&3).
__global__ __launch_bounds__(256) void prep_kernel(
    const float* __restrict__ h1, const float* __restrict__ h2,
    u8* __restrict__ A, u8* __restrict__ B,
    float* __restrict__ sq1, float* __restrict__ s1,
    float* __restrict__ sq2, float* __restrict__ s2) {
  int b = blockIdx.x;
  const float* src; u8* dst; float* sqo; float* so; int row;
  if (b < BS) { src = h1; dst = A; sqo = sq1; so = s1; row = b; }
  else        { src = h2; dst = B; sqo = sq2; so = s2; row = b - BS; }
  src += (size_t)row * DIM;
  dst += (size_t)row * DIM;
  int t = threadIdx.x;
  int idx = t * 8;
  float4 v0 = *(const float4*)(src + idx);
  float4 v1 = *(const float4*)(src + idx + 4);
  float sq = v0.x*v0.x + v0.y*v0.y + v0.z*v0.z + v0.w*v0.w
           + v1.x*v1.x + v1.y*v1.y + v1.z*v1.z + v1.w*v1.w;
  float s  = v0.x + v0.y + v0.z + v0.w + v1.x + v1.y + v1.z + v1.w;
  u64 pk = (u64)f2e4m3(v0.x)
         | ((u64)f2e4m3(v0.y) << 8)
         | ((u64)f2e4m3(v0.z) << 16)
         | ((u64)f2e4m3(v0.w) << 24)
         | ((u64)f2e4m3(v1.x) << 32)
         | ((u64)f2e4m3(v1.y) << 40)
         | ((u64)f2e4m3(v1.z) << 48)
         | ((u64)f2e4m3(v1.w) << 56);
  int vswz = (row >> 2) & 3;
  int dstIdx = (t >> 2) * 32 + (((t & 3) ^ vswz) << 3);
  *(u64*)(dst + dstIdx) = pk;
#pragma unroll
  for (int m = 32; m; m >>= 1) { sq += __shfl_xor(sq, m, 64); s += __shfl_xor(s, m, 64); }
  __shared__ float lsq[4], ls[4];
  if ((t & 63) == 0) { lsq[t >> 6] = sq; ls[t >> 6] = s; }
  __syncthreads();
  if (t == 0) {
    sqo[row] = lsq[0] + lsq[1] + lsq[2] + lsq[3];
    so[row]  = ls[0] + ls[1] + ls[2] + ls[3];
  }
}

// ---------------- GEMM (fp8 e4m3): 256x128 tile, BK=64 (2x K32 sub-arrays), dbuf, 2 blocks/CU ---
// R25-verified best: 72.2 us, MfmaUtil 38.8%, conflicts 0, VGPR 60, no spill, absmax 0.0.
// One __syncthreads per K64 (32 barriers; ~0.38 us/barrier dead time measured R24->R25).
// LDS = 2 buf x [2 khalf x (A 8KB | B 4KB)] = 48 KB -> 2 blocks/CU.
#define BK64 64
#define NT64 (DIM / BK64)

__global__ __launch_bounds__(512, 4) void gemm_select_kernel(
    const u8* __restrict__ A, const u8* __restrict__ B,
    const float* __restrict__ sq1, const float* __restrict__ s1,
    const float* __restrict__ sq2, const float* __restrict__ s2,
    const int* __restrict__ lab1, const int* __restrict__ lab2,
    float4* __restrict__ part) {
  __shared__ __align__(16) u8 lds[2][2][12288];  // [buf][khalf][A 8192 | B 4096]
  int tid = threadIdx.x;
  int w = tid >> 6, l = tid & 63;
  int wr = w >> 1, wc = w & 1;
  int g = l >> 4, c = l & 15;
  int by = blockIdx.x >> 5, bx = blockIdx.x & 31;
  const int rowB = by * 256, colB = bx * 128;

  // linear staging (R19-verified): 2 lanes per 32B row; lane covers 16B half (tid&1)
  int srow = tid >> 1;
  int khalf16 = (tid & 1) * 16;
  const u8* gA = A + (size_t)(rowB + srow) * DIM + khalf16;            // all 512 thr
  const u8* gB = B + (size_t)(colB + (srow & 127)) * DIM + khalf16;    // tid<256 only

#define STAGE(T) do { int b_ = (T) & 1; size_t k_ = (size_t)(T) * BK64;  \
    gload16(gA + k_,      &lds[b_][0][tid * 16]);                         \
    gload16(gA + k_ + 32, &lds[b_][1][tid * 16]);                         \
    if (tid < 256) {                                                      \
      gload16(gB + k_,      &lds[b_][0][8192 + tid * 16]);                \
      gload16(gB + k_ + 32, &lds[b_][1][8192 + tid * 16]); } } while (0)

  // fragment reads: slot = g ^ ((c>>2)&3) -> conflict-free b64 (R18/R19-verified)
  const int slot = (g ^ ((c >> 2) & 3)) * 8;

  f32x4 acc[4][4] = {};

  STAGE(0);
  __syncthreads();

  for (int kt = 0; kt < NT64; ++kt) {
    if (kt + 1 < NT64) STAGE(kt + 1);
#pragma unroll
    for (int h = 0; h < 2; ++h) {
      const u8* buf = lds[kt & 1][h];
      i64 af[4], bfr[4];
#pragma unroll
      for (int mi = 0; mi < 4; ++mi)
        af[mi] = *(const i64*)&buf[(wr * 64 + mi * 16 + c) * 32 + slot];
#pragma unroll
      for (int ni = 0; ni < 4; ++ni)
        bfr[ni] = *(const i64*)&buf[8192 + (wc * 64 + ni * 16 + c) * 32 + slot];
#pragma unroll
      for (int mi = 0; mi < 4; ++mi)
#pragma unroll
        for (int ni = 0; ni < 4; ++ni)
          acc[mi][ni] = __builtin_amdgcn_mfma_f32_16x16x32_fp8_fp8(af[mi], bfr[ni], acc[mi][ni], 0, 0, 0);
    }
    __syncthreads();
  }
#undef STAGE

  // --- epilogue: dist + fused hard-pos/neg partial select (R17/R19/R21-verified) ---
  float pc_[4]; int l2v[4]; int jcol[4];
#pragma unroll
  for (int ni = 0; ni < 4; ++ni) {
    int j = colB + wc * 64 + ni * 16 + c;
    jcol[ni] = j;
    l2v[ni] = lab2[j];
    pc_[ni] = sq2[j] - 2.0f * EPSV * s2[j];
  }
  const float cst = (float)DIM * EPSV * EPSV;
  int partCol = bx * 2 + wc;

#pragma unroll
  for (int mi = 0; mi < 4; ++mi) {
    float posV[4], negV[4]; int posI[4], negI[4];
    float pr[4]; int l1v[4];
#pragma unroll
    for (int r = 0; r < 4; ++r) {
      int i = rowB + wr * 64 + mi * 16 + g * 4 + r;
      l1v[r] = lab1[i];
      pr[r] = sq1[i] + 2.0f * EPSV * s1[i] + cst;
      posV[r] = -3.0e38f; posI[r] = 0x7fffffff;
      negV[r] =  3.0e38f; negI[r] = 0x7fffffff;
    }
#pragma unroll
    for (int ni = 0; ni < 4; ++ni) {
#pragma unroll
      for (int r = 0; r < 4; ++r) {
        float dot = acc[mi][ni][r];
        float d2 = pr[r] + pc_[ni] - 2.0f * dot;
        float dist = sqrtf(fmaxf(d2, 0.0f));
        bool same = (l1v[r] == l2v[ni]);
        float pv = same ? dist : -3.0e38f;
        float nv = same ?  3.0e38f : dist;
        if (pv > posV[r] || (pv == posV[r] && jcol[ni] < posI[r])) { posV[r] = pv; posI[r] = jcol[ni]; }
        if (nv < negV[r] || (nv == negV[r] && jcol[ni] < negI[r])) { negV[r] = nv; negI[r] = jcol[ni]; }
      }
    }
#pragma unroll
    for (int m = 1; m < 16; m <<= 1) {
#pragma unroll
      for (int r = 0; r < 4; ++r) {
        float ov = __shfl_xor(posV[r], m, 64);
        int   oi = __shfl_xor(posI[r], m, 64);
        if (ov > posV[r] || (ov == posV[r] && oi < posI[r])) { posV[r] = ov; posI[r] = oi; }
        float nv2 = __shfl_xor(negV[r], m, 64);
        int   on  = __shfl_xor(negI[r], m, 64);
        if (nv2 < negV[r] || (nv2 == negV[r] && on < negI[r])) { negV[r] = nv2; negI[r] = on; }
      }
    }
    if (c == 0) {
#pragma unroll
      for (int r = 0; r < 4; ++r) {
        int i = rowB + wr * 64 + mi * 16 + g * 4 + r;
        float4 o;
        o.x = posV[r]; o.y = __int_as_float(posI[r]);
        o.z = negV[r]; o.w = __int_as_float(negI[r]);
        part[(size_t)i * 64 + partCol] = o;
      }
    }
  }
}

// ---------------- combine 64 partials per row -> per-row loss directly (R21-verified) -----------
__global__ __launch_bounds__(256) void reduce_kernel(const float4* __restrict__ part,
                                                     float* __restrict__ perrow,
                                                     float* __restrict__ validf) {
  int row = blockIdx.x * 4 + (threadIdx.x >> 6);
  int lane = threadIdx.x & 63;
  float4 p = part[(size_t)row * 64 + lane];
  float posV = p.x; int posI = __float_as_int(p.y);
  float negV = p.z; int negI = __float_as_int(p.w);
#pragma unroll
  for (int m = 1; m < 64; m <<= 1) {
    float ov = __shfl_xor(posV, m, 64);
    int   oi = __shfl_xor(posI, m, 64);
    if (ov > posV || (ov == posV && oi < posI)) { posV = ov; posI = oi; }
    float nv = __shfl_xor(negV, m, 64);
    int   on = __shfl_xor(negI, m, 64);
    if (nv < negV || (nv == negV && on < negI)) { negV = nv; negI = on; }
  }
  if (lane == 0) {
    bool valid = (posV > -1.0e38f && negV < 1.0e38f);
    perrow[row] = valid ? fmaxf(posV - negV, 0.0f) : 0.0f;
    validf[row] = valid ? 1.0f : 0.0f;
  }
}

// ---------------- deterministic finalize (fixed-order tree) ----------------
__global__ __launch_bounds__(256) void finalize_kernel(const float* __restrict__ perrow,
                                                       const float* __restrict__ validf,
                                                       float* __restrict__ out) {
  int t = threadIdx.x;
  float s = 0.f, cv = 0.f;
  for (int i = t; i < BS; i += 256) { s += perrow[i]; cv += validf[i]; }
  __shared__ float ls[256], lc[256];
  ls[t] = s; lc[t] = cv;
  __syncthreads();
  for (int m = 128; m; m >>= 1) {
    if (t < m) { ls[t] += ls[t + m]; lc[t] += lc[t + m]; }
    __syncthreads();
  }
  if (t == 0) out[0] = (lc[0] > 0.f) ? ls[0] / fmaxf(lc[0], 1.f) : 0.f;
}

extern "C" void kernel_launch(void* const* d_in, const int* in_sizes, int n_in,
                              void* d_out, int out_size, void* d_ws, size_t ws_size,
                              hipStream_t stream) {
  const float* h1 = (const float*)d_in[0];
  const float* h2 = (const float*)d_in[1];
  const int* lab1 = (const int*)d_in[2];
  const int* lab2 = (const int*)d_in[3];

  char* ws = (char*)d_ws;
  u8* A = (u8*)ws;
  u8* B = (u8*)(ws + (size_t)BS * DIM);
  size_t off = (size_t)BS * DIM * 2;
  float* sq1 = (float*)(ws + off); off += BS * 4;
  float* s1  = (float*)(ws + off); off += BS * 4;
  float* sq2 = (float*)(ws + off); off += BS * 4;
  float* s2  = (float*)(ws + off); off += BS * 4;
  float4* part = (float4*)(ws + off); off += (size_t)BS * 64 * 16;
  float* perrow = (float*)(ws + off); off += BS * 4;
  float* validf = (float*)(ws + off); off += BS * 4;

  prep_kernel<<<2 * BS, 256, 0, stream>>>(h1, h2, A, B, sq1, s1, sq2, s2);
  gemm_select_kernel<<<512, 512, 0, stream>>>(A, B, sq1, s1, sq2, s2, lab1, lab2, part);
  reduce_kernel<<<BS / 4, 256, 0, stream>>>(part, perrow, validf);
  finalize_kernel<<<1, 256, 0, stream>>>(perrow, validf, (float*)d_out);
}